// Round 9
// baseline (65.525 us; speedup 1.0000x reference)
//
#include <hip/hip_runtime.h>
#include <hip/hip_bf16.h>
#include <math.h>

#define NSPK 2048
#define G 10
#define D 256
#define NG (NSPK * G)
#define LOG2E 1.4426950408889634f
#define LN2   0.6931471805599453f

typedef __attribute__((ext_vector_type(8))) short bf16x8;
typedef __attribute__((ext_vector_type(4))) short short4v;
typedef __attribute__((ext_vector_type(16))) float f32x16;

__device__ __forceinline__ float dot4(float4 a, float4 b) {
    return a.x * b.x + a.y * b.y + a.z * b.z + a.w * b.w;
}
__device__ __forceinline__ short bf(float v) {
    return (short)__bfloat16_as_ushort(__float2bfloat16(v));
}

// ---------------- Kernel A: per-speaker prep (wave-per-speaker) ----------------
// Writes BOTH matrices in MFMA fragment order (elem (r,d) at shorts-addr
//   (r>>5)*8192 + (d>>4)*512 + ((d>>3)&1)*256 + (r&31)*8 + (d&7)):
//   xb2 : normalized x rows   (B-operand fragments)
//   cbf : normalized centroids (A-operand fragments)  -> gemm needs NO LDS
//   dlarg[r] = (w*clip(cos(x_r, exc_centroid)) + b - 5) * log2(e)
__global__ __launch_bounds__(256) void prep_kernel(
    const float* __restrict__ x, const float* __restrict__ wp, const float* __restrict__ bp,
    short* __restrict__ xb2, short* __restrict__ cbf, float* __restrict__ dlarg)
{
    const int lane = threadIdx.x & 63;
    const int n = blockIdx.x * 4 + (threadIdx.x >> 6);
    const float* xr = x + (size_t)n * G * D + lane * 4;

    float4 xg[G];
    float4 S4 = {0.f, 0.f, 0.f, 0.f};
    #pragma unroll
    for (int g = 0; g < G; ++g) {
        xg[g] = *(const float4*)(xr + g * D);
        S4.x += xg[g].x; S4.y += xg[g].y; S4.z += xg[g].z; S4.w += xg[g].w;
    }

    float arr[20];
    #pragma unroll
    for (int g = 0; g < G; ++g) {
        arr[g]      = dot4(xg[g], xg[g]);   // xx
        arr[10 + g] = dot4(xg[g], S4);      // xs
    }
    #pragma unroll
    for (int i = 0; i < 20; ++i) {
        float v = arr[i];
        #pragma unroll
        for (int off = 1; off < 64; off <<= 1) v += __shfl_xor(v, off);
        arr[i] = v;
    }
    float SS = 0.f;
    #pragma unroll
    for (int g = 0; g < G; ++g) SS += arr[10 + g];

    const int ks  = lane >> 2;          // fragment coords for d = lane*4..+3
    const int l5b = (lane >> 1) & 1;
    const int j0  = (lane & 1) * 4;

    // centroid (norm folded), fragment layout
    const float cn = fmaxf(sqrtf(SS) * (1.0f / G), 1e-8f);
    const float cinv = (1.0f / G) / cn;
    short4v cv = { bf(S4.x * cinv), bf(S4.y * cinv), bf(S4.z * cinv), bf(S4.w * cinv) };
    *(short4v*)(cbf + (size_t)(n >> 5) * 8192 + ks * 512 + l5b * 256 + (n & 31) * 8 + j0) = cv;

    // normalized x rows, fragment layout
    #pragma unroll
    for (int g = 0; g < G; ++g) {
        const int r = n * G + g;
        const float inv = 1.0f / fmaxf(sqrtf(arr[g]), 1e-8f);
        short4v xv = { bf(xg[g].x * inv), bf(xg[g].y * inv), bf(xg[g].z * inv), bf(xg[g].w * inv) };
        *(short4v*)(xb2 + (size_t)(r >> 5) * 8192 + ks * 512 + l5b * 256 + (r & 31) * 8 + j0) = xv;
    }

    if (lane < G) {
        const int g = lane;
        const float w = *wp, b = *bp;
        const float xx = arr[g], xs = arr[10 + g];
        const float x_norm = fmaxf(sqrtf(xx), 1e-8f);
        const float dotxe = (xs - xx) * (1.0f / (G - 1));
        const float ee = (SS - 2.f * xs + xx) * (1.0f / ((G - 1) * (G - 1)));
        const float e_norm = fmaxf(sqrtf(ee), 1e-8f);
        float cosd = fmaxf(dotxe / (x_norm * e_norm), 1e-6f);
        dlarg[n * G + g] = (fmaf(w, cosd, b) - 5.0f) * LOG2E;
    }
}

// ---------------- Kernel B: LDS-free MFMA GEMM + fixed-max LSE ----------------
// Block: 2 waves x 64 rows (2 rowsets) = 128 rows x 256 cols; grid 1280
// (exactly 5 blocks/CU of work). No LDS, no barriers: cbf is read in fragment
// order as coalesced global loads (uniform base + lane*16B) served by L1/L2.
// Each cf load feeds 2 MFMAs (two row-set acc chains) -> halves cache traffic,
// doubles MFMA ILP. XCD swizzle keeps each row-tile's col-splits on one XCD.
__global__ __launch_bounds__(128, 2) void gemm_softmax_kernel(
    const short* __restrict__ xb2, const short* __restrict__ cbf,
    const float* __restrict__ dlarg,
    const float* __restrict__ wp, const float* __restrict__ bp,
    float* __restrict__ pm, float* __restrict__ ps)
{
    const int tid = threadIdx.x;
    const int wv = tid >> 6, lane = tid & 63;
    const int l31 = lane & 31, l5 = lane >> 5;

    // XCD-aware decode: rt ≡ bid (mod 8)
    const int bid = blockIdx.x;
    const int xcd = bid & 7;
    const int idx = bid >> 3;             // 0..159
    const int rt = xcd + 8 * (idx % 20);  // 0..159
    const int cs = idx / 20;              // 0..7

    const int r0 = rt * 128, c0 = cs * 256;
    const int rowA = r0 + wv * 64 + l31;  // rowset A
    const int rowB = rowA + 32;           // rowset B
    const float w2 = (*wp) * LOG2E;
    const float b2 = ((*bp) - 5.0f) * LOG2E;
    const float dlA = dlarg[rowA], dlB = dlarg[rowB];
    const int labadjA = rowA / G - c0 - 4 * l5;
    const int labadjB = rowB / G - c0 - 4 * l5;

    // resident x fragments, two row-sets (coalesced: fragment-order layout)
    bf16x8 xfA[16], xfB[16];
    const short* xrowA = xb2 + (size_t)(rt * 4 + wv * 2) * 8192 + lane * 8;
    #pragma unroll
    for (int ks = 0; ks < 16; ++ks) {
        xfA[ks] = *(const bf16x8*)(xrowA + ks * 512);
        xfB[ks] = *(const bf16x8*)(xrowA + 8192 + ks * 512);
    }

    float sA0 = 0.f, sA1 = 0.f, mA0 = -INFINITY, mA1 = -INFINITY;
    float sB0 = 0.f, sB1 = 0.f, mB0 = -INFINITY, mB1 = -INFINITY;

    for (int t = 0; t < 8; ++t) {
        const short* cfb = cbf + (size_t)((c0 >> 5) + t) * 8192 + lane * 8;

        f32x16 acc0 = {0,0,0,0,0,0,0,0,0,0,0,0,0,0,0,0};
        f32x16 acc1 = {0,0,0,0,0,0,0,0,0,0,0,0,0,0,0,0};
        #pragma unroll
        for (int ks = 0; ks < 16; ++ks) {
            const bf16x8 cf = *(const bf16x8*)(cfb + ks * 512);
            acc0 = __builtin_amdgcn_mfma_f32_32x32x16_bf16(cf, xfA[ks], acc0, 0, 0, 0);
            acc1 = __builtin_amdgcn_mfma_f32_32x32x16_bf16(cf, xfB[ks], acc1, 0, 0, 0);
        }

        // epilogue rowset A (in place on acc0)
        {
            const int target = labadjA - t * 32;
            if ((unsigned)target < 32u && !(target & 4)) {
                #pragma unroll
                for (int reg = 0; reg < 16; ++reg) {
                    const int pat = (reg & 3) + 8 * (reg >> 2);
                    if (pat == target) acc0[reg] = (dlA - b2) / w2;
                }
            }
            #pragma unroll
            for (int reg = 0; reg < 16; ++reg) {
                const float larg = fmaf(w2, fmaxf(acc0[reg], 1e-6f), b2);
                const float e = exp2f(larg);
                if (reg & 1) { sA1 += e; mA1 = fmaxf(mA1, larg); }
                else         { sA0 += e; mA0 = fmaxf(mA0, larg); }
            }
        }
        // epilogue rowset B (in place on acc1)
        {
            const int target = labadjB - t * 32;
            if ((unsigned)target < 32u && !(target & 4)) {
                #pragma unroll
                for (int reg = 0; reg < 16; ++reg) {
                    const int pat = (reg & 3) + 8 * (reg >> 2);
                    if (pat == target) acc1[reg] = (dlB - b2) / w2;
                }
            }
            #pragma unroll
            for (int reg = 0; reg < 16; ++reg) {
                const float larg = fmaf(w2, fmaxf(acc1[reg], 1e-6f), b2);
                const float e = exp2f(larg);
                if (reg & 1) { sB1 += e; mB1 = fmaxf(mB1, larg); }
                else         { sB0 += e; mB0 = fmaxf(mB0, larg); }
            }
        }
    }

    float sA = sA0 + sA1, sB = sB0 + sB1;
    float mA = fmaxf(mA0, mA1), mB = fmaxf(mB0, mB1);
    sA += __shfl_xor(sA, 32);  mA = fmaxf(mA, __shfl_xor(mA, 32));
    sB += __shfl_xor(sB, 32);  mB = fmaxf(mB, __shfl_xor(mB, 32));
    if (lane < 32) {
        pm[cs * NG + rowA] = mA;  ps[cs * NG + rowA] = sA;
        pm[cs * NG + rowB] = mB;  ps[cs * NG + rowB] = sB;
    }
}

// ---------------- Kernel C: merge column-split partials + block partial sums ----
__global__ __launch_bounds__(256) void merge_kernel(
    const float* __restrict__ pm, const float* __restrict__ ps,
    const float* __restrict__ dlarg,
    float* __restrict__ part_loss, float* __restrict__ part_corr)
{
    const int r = blockIdx.x * 256 + threadIdx.x;
    float M = -INFINITY, S = 0.f;
    #pragma unroll
    for (int c = 0; c < 8; ++c) {
        M = fmaxf(M, pm[c * NG + r]);
        S += ps[c * NG + r];
    }
    const float dlv = dlarg[r];
    float loss = LN2 * (log2f(S) - dlv);
    float corr = (M == dlv) ? 1.0f : 0.0f;

    #pragma unroll
    for (int off = 1; off < 64; off <<= 1) {
        loss += __shfl_xor(loss, off);
        corr += __shfl_xor(corr, off);
    }
    __shared__ float rl[4], rc[4];
    const int wave = threadIdx.x >> 6, lane = threadIdx.x & 63;
    if (lane == 0) { rl[wave] = loss; rc[wave] = corr; }
    __syncthreads();
    if (threadIdx.x == 0) {
        part_loss[blockIdx.x] = rl[0] + rl[1] + rl[2] + rl[3];
        part_corr[blockIdx.x] = rc[0] + rc[1] + rc[2] + rc[3];
    }
}

// ---------------- Kernel D: final tiny reduction (80 partials) ----------------
__global__ __launch_bounds__(64) void finalize_kernel(
    const float* __restrict__ part_loss, const float* __restrict__ part_corr,
    float* __restrict__ out)
{
    const int t = threadIdx.x;
    float ls = (t < 80 ? part_loss[t] : 0.f) + (t + 64 < 80 ? part_loss[t + 64] : 0.f);
    float cs = (t < 80 ? part_corr[t] : 0.f) + (t + 64 < 80 ? part_corr[t + 64] : 0.f);
    #pragma unroll
    for (int off = 1; off < 64; off <<= 1) { ls += __shfl_xor(ls, off); cs += __shfl_xor(cs, off); }
    if (t == 0) {
        out[0] = ls / (float)NG;
        out[1] = 100.0f * cs / (float)NG;
    }
}

extern "C" void kernel_launch(void* const* d_in, const int* in_sizes, int n_in,
                              void* d_out, int out_size, void* d_ws, size_t ws_size,
                              hipStream_t stream) {
    const float* x  = (const float*)d_in[0];
    const float* wp = (const float*)d_in[1];
    const float* bp = (const float*)d_in[2];

    short* xb2 = (short*)d_ws;                             // NG*D shorts   = 10.5 MB
    short* cbf = xb2 + (size_t)NG * D;                     // NSPK*D shorts = 1.05 MB
    float* dlg = (float*)(cbf + (size_t)NSPK * D);         // NG floats
    float* pm  = dlg + NG;                                 // 8*NG
    float* ps  = pm + 8 * NG;                              // 8*NG
    float* pl  = ps + 8 * NG;                              // 80
    float* pc  = pl + 128;                                 // 80

    prep_kernel<<<NSPK / 4, 256, 0, stream>>>(x, wp, bp, xb2, cbf, dlg);
    gemm_softmax_kernel<<<1280, 128, 0, stream>>>(xb2, cbf, dlg, wp, bp, pm, ps);
    merge_kernel<<<NG / 256, 256, 0, stream>>>(pm, ps, dlg, pl, pc);
    finalize_kernel<<<1, 64, 0, stream>>>(pl, pc, (float*)d_out);
}

// Round 10
// 53.069 us; speedup vs baseline: 1.2347x; 1.2347x over previous
//
#include <hip/hip_runtime.h>
#include <hip/hip_bf16.h>
#include <math.h>

#define NSPK 2048
#define G 10
#define D 256
#define NG (NSPK * G)
#define LOG2E 1.4426950408889634f
#define LN2   0.6931471805599453f

typedef __attribute__((ext_vector_type(8))) short bf16x8;
typedef __attribute__((ext_vector_type(4))) short short4v;
typedef __attribute__((ext_vector_type(16))) float f32x16;

__device__ __forceinline__ float dot4(float4 a, float4 b) {
    return a.x * b.x + a.y * b.y + a.z * b.z + a.w * b.w;
}
__device__ __forceinline__ short bf(float v) {
    return (short)__bfloat16_as_ushort(__float2bfloat16(v));
}

// ---------------- Kernel A: per-speaker prep (wave-per-speaker) ----------------
// Writes:
//   xb2 : normalized x rows, bf16, MFMA B-fragment order:
//         addr(shorts) = (r>>5)*8192 + (d>>4)*512 + ((d>>3)&1)*256 + (r&31)*8 + (d&7)
//   cb  : normalized centroids, bf16, natural [NSPK][D] (staged via LDS in gemm)
//   dlarg[r] = (w*clip(cos(x_r, exc_centroid)) + b - 5) * log2(e)
__global__ __launch_bounds__(256) void prep_kernel(
    const float* __restrict__ x, const float* __restrict__ wp, const float* __restrict__ bp,
    short* __restrict__ xb2, short* __restrict__ cb, float* __restrict__ dlarg)
{
    const int lane = threadIdx.x & 63;
    const int n = blockIdx.x * 4 + (threadIdx.x >> 6);
    const float* xr = x + (size_t)n * G * D + lane * 4;

    float4 xg[G];
    float4 S4 = {0.f, 0.f, 0.f, 0.f};
    #pragma unroll
    for (int g = 0; g < G; ++g) {
        xg[g] = *(const float4*)(xr + g * D);
        S4.x += xg[g].x; S4.y += xg[g].y; S4.z += xg[g].z; S4.w += xg[g].w;
    }

    float arr[20];
    #pragma unroll
    for (int g = 0; g < G; ++g) {
        arr[g]      = dot4(xg[g], xg[g]);   // xx
        arr[10 + g] = dot4(xg[g], S4);      // xs
    }
    #pragma unroll
    for (int i = 0; i < 20; ++i) {
        float v = arr[i];
        #pragma unroll
        for (int off = 1; off < 64; off <<= 1) v += __shfl_xor(v, off);
        arr[i] = v;
    }
    float SS = 0.f;
    #pragma unroll
    for (int g = 0; g < G; ++g) SS += arr[10 + g];

    // centroid (norm folded), natural layout
    const float cn = fmaxf(sqrtf(SS) * (1.0f / G), 1e-8f);
    const float cinv = (1.0f / G) / cn;
    short4v cv = { bf(S4.x * cinv), bf(S4.y * cinv), bf(S4.z * cinv), bf(S4.w * cinv) };
    *(short4v*)(cb + (size_t)n * D + lane * 4) = cv;

    // normalized x rows, fragment layout
    const int ks  = lane >> 2;
    const int l5b = (lane >> 1) & 1;
    const int j0  = (lane & 1) * 4;
    #pragma unroll
    for (int g = 0; g < G; ++g) {
        const int r = n * G + g;
        const float inv = 1.0f / fmaxf(sqrtf(arr[g]), 1e-8f);
        short4v xv = { bf(xg[g].x * inv), bf(xg[g].y * inv), bf(xg[g].z * inv), bf(xg[g].w * inv) };
        *(short4v*)(xb2 + (size_t)(r >> 5) * 8192 + ks * 512 + l5b * 256 + (r & 31) * 8 + j0) = xv;
    }

    if (lane < G) {
        const int g = lane;
        const float w = *wp, b = *bp;
        const float xx = arr[g], xs = arr[10 + g];
        const float x_norm = fmaxf(sqrtf(xx), 1e-8f);
        const float dotxe = (xs - xx) * (1.0f / (G - 1));
        const float ee = (SS - 2.f * xs + xx) * (1.0f / ((G - 1) * (G - 1)));
        const float e_norm = fmaxf(sqrtf(ee), 1e-8f);
        float cosd = fmaxf(dotxe / (x_norm * e_norm), 1e-6f);
        dlarg[n * G + g] = (fmaf(w, cosd, b) - 5.0f) * LOG2E;
    }
}

// ---------------- Kernel B: LDS-staged MFMA GEMM, 2 rowsets/wave ---------------
// Block: 2 waves x 64 rows = 128 rows x 256 cols; grid 1280 (5 blocks/CU).
// Each staged cf tile (16 KB, dbuf, XOR-swizzled, coalesced global_load_lds)
// is read ONCE per wave per tile (16 ds_read_b128) and feeds 32 MFMAs
// (2 rowset acc chains) -> ds_read pipe (prev floor, 12.8us/CU) halves to
// 6.4us/CU, below the 8.5us MFMA floor. Counted vmcnt(8), raw barriers.
__global__ __launch_bounds__(128, 2) void gemm_softmax_kernel(
    const short* __restrict__ xb2, const short* __restrict__ cb,
    const float* __restrict__ dlarg,
    const float* __restrict__ wp, const float* __restrict__ bp,
    float* __restrict__ pm, float* __restrict__ ps)
{
    __shared__ __align__(16) unsigned short stage[2][8192];   // 2 x 16 KB

    const int tid = threadIdx.x;
    const int wv = tid >> 6, lane = tid & 63;
    const int l31 = lane & 31, l5 = lane >> 5;

    // XCD-aware decode: rt ≡ bid (mod 8)
    const int bid = blockIdx.x;
    const int xcd = bid & 7;
    const int idx = bid >> 3;             // 0..159
    const int rt = xcd + 8 * (idx % 20);  // 0..159
    const int cs = idx / 20;              // 0..7

    const int r0 = rt * 128, c0 = cs * 256;
    const int rowA = r0 + wv * 64 + l31;  // rowset A
    const int rowB = rowA + 32;           // rowset B
    const float w2 = (*wp) * LOG2E;
    const float b2 = ((*bp) - 5.0f) * LOG2E;
    const float dlA = dlarg[rowA], dlB = dlarg[rowB];
    const int labadjA = rowA / G - c0 - 4 * l5;
    const int labadjB = rowB / G - c0 - 4 * l5;

    // resident x fragments, two row-sets (coalesced: fragment-order layout)
    bf16x8 xfA[16], xfB[16];
    const short* xrowA = xb2 + (size_t)(rt * 4 + wv * 2) * 8192 + lane * 8;
    #pragma unroll
    for (int ks = 0; ks < 16; ++ks) {
        xfA[ks] = *(const bf16x8*)(xrowA + ks * 512);
        xfB[ks] = *(const bf16x8*)(xrowA + 8192 + ks * 512);
    }

    // staging source offsets (pre-swizzled), 8 calls/wave, 16B/lane
    const unsigned char* cbb = (const unsigned char*)cb;
    unsigned int src_off[8];
    #pragma unroll
    for (int c = 0; c < 8; ++c) {
        const int slot = c * 128 + tid;               // 0..1023
        const int i = slot >> 5;                      // row in 32-row tile
        const int w32 = slot & 31;                    // 16B-slot in row
        src_off[c] = (unsigned int)((c0 + i) * 512 + ((w32 ^ i) << 4));
    }

    #define STAGE(bufi, tt) do {                                               \
        const unsigned char* base_ = cbb + (size_t)(tt) * 16384;               \
        _Pragma("unroll")                                                      \
        for (int c_ = 0; c_ < 8; ++c_) {                                       \
            __builtin_amdgcn_global_load_lds(                                  \
                (const __attribute__((address_space(1))) void*)(base_ + src_off[c_]), \
                (__attribute__((address_space(3))) void*)                      \
                    ((unsigned char*)&stage[bufi][0] + c_ * 2048 + wv * 1024), \
                16, 0, 0);                                                     \
        }                                                                      \
    } while (0)

    STAGE(0, 0);
    STAGE(1, 1);

    float sA0 = 0.f, sA1 = 0.f, mA0 = -INFINITY, mA1 = -INFINITY;
    float sB0 = 0.f, sB1 = 0.f, mB0 = -INFINITY, mB1 = -INFINITY;
    const int rbase = l31 * 32;

    for (int t = 0; t < 8; ++t) {
        const int bsel = t & 1;
        // counted wait: tile t's 8 staging loads done; tile t+1's stay in flight
        if (t < 7) { asm volatile("s_waitcnt vmcnt(8)" ::: "memory"); }
        else       { asm volatile("s_waitcnt vmcnt(0)" ::: "memory"); }
        __builtin_amdgcn_s_barrier();
        __builtin_amdgcn_sched_barrier(0);

        f32x16 acc0 = {0,0,0,0,0,0,0,0,0,0,0,0,0,0,0,0};
        f32x16 acc1 = {0,0,0,0,0,0,0,0,0,0,0,0,0,0,0,0};
        __builtin_amdgcn_s_setprio(1);
        #pragma unroll
        for (int ks = 0; ks < 16; ++ks) {
            const int slot = rbase + ((2 * ks + l5) ^ l31);
            const bf16x8 cf = *(const bf16x8*)(&stage[bsel][slot * 8]);
            acc0 = __builtin_amdgcn_mfma_f32_32x32x16_bf16(cf, xfA[ks], acc0, 0, 0, 0);
            acc1 = __builtin_amdgcn_mfma_f32_32x32x16_bf16(cf, xfB[ks], acc1, 0, 0, 0);
        }
        __builtin_amdgcn_s_setprio(0);
        __builtin_amdgcn_sched_barrier(0);
        __builtin_amdgcn_s_barrier();

        if (t < 6) STAGE(bsel, t + 2);   // refill; lands during next tile's compute

        // epilogue rowset A (in place on acc0)
        {
            const int target = labadjA - t * 32;
            if ((unsigned)target < 32u && !(target & 4)) {
                #pragma unroll
                for (int reg = 0; reg < 16; ++reg) {
                    const int pat = (reg & 3) + 8 * (reg >> 2);
                    if (pat == target) acc0[reg] = (dlA - b2) / w2;
                }
            }
            #pragma unroll
            for (int reg = 0; reg < 16; reg += 2) {
                const float l0 = fmaf(w2, fmaxf(acc0[reg],     1e-6f), b2);
                const float l1 = fmaf(w2, fmaxf(acc0[reg + 1], 1e-6f), b2);
                sA0 += exp2f(l0);
                sA1 += exp2f(l1);
                mA0 = fmaxf(mA0, fmaxf(l0, l1));   // fuses to v_max3_f32
            }
        }
        // epilogue rowset B (in place on acc1)
        {
            const int target = labadjB - t * 32;
            if ((unsigned)target < 32u && !(target & 4)) {
                #pragma unroll
                for (int reg = 0; reg < 16; ++reg) {
                    const int pat = (reg & 3) + 8 * (reg >> 2);
                    if (pat == target) acc1[reg] = (dlB - b2) / w2;
                }
            }
            #pragma unroll
            for (int reg = 0; reg < 16; reg += 2) {
                const float l0 = fmaf(w2, fmaxf(acc1[reg],     1e-6f), b2);
                const float l1 = fmaf(w2, fmaxf(acc1[reg + 1], 1e-6f), b2);
                sB0 += exp2f(l0);
                sB1 += exp2f(l1);
                mB0 = fmaxf(mB0, fmaxf(l0, l1));
            }
        }
    }
    #undef STAGE

    float sA = sA0 + sA1, sB = sB0 + sB1;
    float mA = fmaxf(mA0, mA1), mB = fmaxf(mB0, mB1);
    sA += __shfl_xor(sA, 32);  mA = fmaxf(mA, __shfl_xor(mA, 32));
    sB += __shfl_xor(sB, 32);  mB = fmaxf(mB, __shfl_xor(mB, 32));
    if (lane < 32) {
        pm[cs * NG + rowA] = mA;  ps[cs * NG + rowA] = sA;
        pm[cs * NG + rowB] = mB;  ps[cs * NG + rowB] = sB;
    }
}

// ---------------- Kernel C: merge column-split partials + block partial sums ----
__global__ __launch_bounds__(256) void merge_kernel(
    const float* __restrict__ pm, const float* __restrict__ ps,
    const float* __restrict__ dlarg,
    float* __restrict__ part_loss, float* __restrict__ part_corr)
{
    const int r = blockIdx.x * 256 + threadIdx.x;
    float M = -INFINITY, S = 0.f;
    #pragma unroll
    for (int c = 0; c < 8; ++c) {
        M = fmaxf(M, pm[c * NG + r]);
        S += ps[c * NG + r];
    }
    const float dlv = dlarg[r];
    float loss = LN2 * (log2f(S) - dlv);
    float corr = (M == dlv) ? 1.0f : 0.0f;

    #pragma unroll
    for (int off = 1; off < 64; off <<= 1) {
        loss += __shfl_xor(loss, off);
        corr += __shfl_xor(corr, off);
    }
    __shared__ float rl[4], rc[4];
    const int wave = threadIdx.x >> 6, lane = threadIdx.x & 63;
    if (lane == 0) { rl[wave] = loss; rc[wave] = corr; }
    __syncthreads();
    if (threadIdx.x == 0) {
        part_loss[blockIdx.x] = rl[0] + rl[1] + rl[2] + rl[3];
        part_corr[blockIdx.x] = rc[0] + rc[1] + rc[2] + rc[3];
    }
}

// ---------------- Kernel D: final tiny reduction (80 partials) ----------------
__global__ __launch_bounds__(64) void finalize_kernel(
    const float* __restrict__ part_loss, const float* __restrict__ part_corr,
    float* __restrict__ out)
{
    const int t = threadIdx.x;
    float ls = (t < 80 ? part_loss[t] : 0.f) + (t + 64 < 80 ? part_loss[t + 64] : 0.f);
    float cs = (t < 80 ? part_corr[t] : 0.f) + (t + 64 < 80 ? part_corr[t + 64] : 0.f);
    #pragma unroll
    for (int off = 1; off < 64; off <<= 1) { ls += __shfl_xor(ls, off); cs += __shfl_xor(cs, off); }
    if (t == 0) {
        out[0] = ls / (float)NG;
        out[1] = 100.0f * cs / (float)NG;
    }
}

extern "C" void kernel_launch(void* const* d_in, const int* in_sizes, int n_in,
                              void* d_out, int out_size, void* d_ws, size_t ws_size,
                              hipStream_t stream) {
    const float* x  = (const float*)d_in[0];
    const float* wp = (const float*)d_in[1];
    const float* bp = (const float*)d_in[2];

    short* xb2 = (short*)d_ws;                             // NG*D shorts   = 10.5 MB
    short* cb  = xb2 + (size_t)NG * D;                     // NSPK*D shorts = 1.05 MB
    float* dlg = (float*)(cb + (size_t)NSPK * D);          // NG floats
    float* pm  = dlg + NG;                                 // 8*NG
    float* ps  = pm + 8 * NG;                              // 8*NG
    float* pl  = ps + 8 * NG;                              // 80
    float* pc  = pl + 128;                                 // 80

    prep_kernel<<<NSPK / 4, 256, 0, stream>>>(x, wp, bp, xb2, cb, dlg);
    gemm_softmax_kernel<<<1280, 128, 0, stream>>>(xb2, cb, dlg, wp, bp, pm, ps);
    merge_kernel<<<NG / 256, 256, 0, stream>>>(pm, ps, dlg, pl, pc);
    finalize_kernel<<<1, 64, 0, stream>>>(pl, pc, (float*)d_out);
}